// Round 1
// 1086.199 us; speedup vs baseline: 1.0124x; 1.0124x over previous
//
#include <hip/hip_runtime.h>

#define Bn 32
#define Kn 512
#define Cn 32

typedef float vf4 __attribute__((ext_vector_type(4)));

// ws layout (float offsets)
#define WTC_OFF   0          // 16384: w_col transposed  wTc[k*32+o]
#define WTR_OFF   16384      // 16384: w_row transposed
#define S_OFF     32768      // 1024: s[b*32+o]

// ---------------- k0: transpose weights to k-major + zero s ----------------
__global__ void k_prep(const float* __restrict__ w_col,
                       const float* __restrict__ w_row,
                       float* __restrict__ ws) {
    if (blockIdx.x == 128) {             // zero s[1024]
        ((vf4*)(ws + S_OFF))[threadIdx.x] = (vf4){0.f, 0.f, 0.f, 0.f};
        return;
    }
    int idx = blockIdx.x * 256 + threadIdx.x;          // 0..32767
    int which = idx >> 14;                             // 0: col, 1: row
    int e = idx & 16383;
    int o = e & 31, k = e >> 5;
    const float* src = which ? w_row : w_col;
    float* dst = ws + (which ? WTR_OFF : WTC_OFF);
    dst[e] = src[o * Kn + k];
}

// ---------------- k1: fused col/row GEMMs + dot-reduce → s ----------------
// grid (8 t-chunks, 32 b) = 256 blocks × 512 threads (8 waves) → 8 waves/CU.
// wave w: phase = w>>2 (0=col, 1=row), kh = w&3 (k-quarter); lane = t (0..63).
// k is wave-uniform ⇒ all weight reads are SGPR s_loads (per round-4 win).
// Per-wave accs → LDS, block forms colPlus·rowPlus, atomicAdd 32 partials.
__global__ __launch_bounds__(512) void k_fused(
    const float* __restrict__ x,      // [B][K][K]
    const float* __restrict__ bcol,
    const float* __restrict__ brow,
    float* __restrict__ ws) {
    const int chunk = blockIdx.x;     // 0..7
    const int b     = blockIdx.y;     // 0..31
    const int t0  = chunk * 64;
    const int tid = threadIdx.x;
    const int t   = tid & 63;                                   // lane
    const int wv  = __builtin_amdgcn_readfirstlane(tid >> 6);   // 0..7
    const int phase = wv >> 2;
    const int kh    = wv & 3;

    __shared__ float buf[8][64 * 33]; // 67.6 KB

    const float* __restrict__ xb = x + b * (Kn * Kn);

    float acc[32];
#pragma unroll
    for (int o = 0; o < 32; ++o) acc[o] = 0.f;

    if (phase == 0) {
        // col[t,o] = sum_k x[t0+t][k] * wTc[k][o] — per-thread contiguous rows
        const float4* __restrict__ xr = (const float4*)(xb + (t0 + t) * Kn) + kh * 32;
        const float* __restrict__ wk = ws + WTC_OFF + kh * 128 * 32;
#pragma unroll 2
        for (int j = 0; j < 32; ++j) {                 // 32 float4 = 128 k
            float4 v = xr[j];
            const float* __restrict__ w0 = wk + j * 128;   // uniform → s_load
#pragma unroll
            for (int o = 0; o < 32; ++o) acc[o] = fmaf(v.x, w0[o],      acc[o]);
#pragma unroll
            for (int o = 0; o < 32; ++o) acc[o] = fmaf(v.y, w0[32 + o], acc[o]);
#pragma unroll
            for (int o = 0; o < 32; ++o) acc[o] = fmaf(v.z, w0[64 + o], acc[o]);
#pragma unroll
            for (int o = 0; o < 32; ++o) acc[o] = fmaf(v.w, w0[96 + o], acc[o]);
        }
    } else {
        // row[t,o] = sum_k x[k][t0+t] * wTr[k][o] — lane-contiguous column reads
        const float* __restrict__ wr = ws + WTR_OFF;
        const int kb = kh * 128;
#pragma unroll 4
        for (int k = 0; k < 128; ++k) {
            float xv = xb[(kb + k) * Kn + t0 + t];
            const float* __restrict__ w = wr + (kb + k) * 32;  // uniform → s_load
#pragma unroll
            for (int o = 0; o < 32; ++o) acc[o] = fmaf(xv, w[o], acc[o]);
        }
    }

    // park all 8 wave-accumulators in LDS (banks: (33t+o)%32 = (t+o)%32, clean)
    {
        float* __restrict__ my = buf[wv] + t * 33;
#pragma unroll
        for (int o = 0; o < 32; ++o) my[o] = acc[o];
    }
    __syncthreads();

    // product-reduce: 512 threads, o = tid&31, g = tid>>5 covers 4 t each
    const int o = tid & 31, g = tid >> 5;            // g: 0..15
    const float bc = bcol[o], br = brow[o];
    float sum = 0.f;
#pragma unroll
    for (int j = 0; j < 4; ++j) {
        const int tt = g * 4 + j;
        const int a  = tt * 33 + o;
        float c = buf[0][a] + buf[1][a] + buf[2][a] + buf[3][a] + bc;
        float r = buf[4][a] + buf[5][a] + buf[6][a] + buf[7][a] + br;
        sum = fmaf(c, r, sum);
    }
    __shared__ float red2[16 * 33];
    red2[g * 33 + o] = sum;
    __syncthreads();
    if (tid < 32) {
        float s = 0.f;
#pragma unroll
        for (int j = 0; j < 16; ++j) s += red2[j * 33 + tid];
        atomicAdd(ws + S_OFF + b * 32 + tid, s);
    }
}

// ---------------- k2: broadcast s to (B,C,512,512) ----------------
// Fill-shaped streaming store kernel: 4096 blocks × 256 threads.
// Each block owns a contiguous 256 KB quarter of one (b,o) plane; each wave
// streams a contiguous 64 KB ascending region with plain (cached) float4
// stores — 1 KB per store instruction, back-to-back. The harness's own
// fillBufferAligned proves this store shape reaches ~6.3 TB/s; nt-stores
// (previous version) bypass the L2 write-combine path and ran far slower.
__global__ __launch_bounds__(256) void k_broadcast(const float* __restrict__ ws,
                                                   float* __restrict__ out) {
    const int bo   = blockIdx.x >> 2;            // 0..1023 (wave-uniform s)
    const int part = blockIdx.x & 3;             // quarter of the 512x512 plane
    const int lane = threadIdx.x & 63;
    const int wv   = threadIdx.x >> 6;
    const float sval = ws[S_OFF + bo];           // uniform → s_load
    vf4 v = (vf4){sval, sval, sval, sval};
    vf4* __restrict__ out4 =
        (vf4*)out + (size_t)bo * 65536 + (size_t)part * 16384
                  + (size_t)wv * 4096 + lane;
#pragma unroll
    for (int j = 0; j < 64; ++j)
        out4[j * 64] = v;                        // contiguous 1 KB/wave/store
}

extern "C" void kernel_launch(void* const* d_in, const int* in_sizes, int n_in,
                              void* d_out, int out_size, void* d_ws, size_t ws_size,
                              hipStream_t stream) {
    const float* x     = (const float*)d_in[0];
    const float* w_col = (const float*)d_in[1];
    const float* b_col = (const float*)d_in[2];
    const float* w_row = (const float*)d_in[3];
    const float* b_row = (const float*)d_in[4];
    float* out = (float*)d_out;
    float* ws  = (float*)d_ws;

    hipLaunchKernelGGL(k_prep, dim3(129), dim3(256), 0, stream, w_col, w_row, ws);
    hipLaunchKernelGGL(k_fused, dim3(8, 32), dim3(512), 0, stream, x, b_col, b_row, ws);
    hipLaunchKernelGGL(k_broadcast, dim3(4096), dim3(256), 0, stream, ws, out);
}

// Round 2
// 1082.312 us; speedup vs baseline: 1.0160x; 1.0036x over previous
//
#include <hip/hip_runtime.h>

#define Bn 32
#define Kn 512
#define Cn 32

typedef float vf4 __attribute__((ext_vector_type(4)));

// ws layout (float offsets)
#define WTC_OFF   0          // 16384: w_col transposed  wTc[k*32+o]
#define WTR_OFF   16384      // 16384: w_row transposed
#define S_OFF     32768      // 1024: s[b*32+o]

// ---------------- k0: transpose weights to k-major + zero s ----------------
__global__ void k_prep(const float* __restrict__ w_col,
                       const float* __restrict__ w_row,
                       float* __restrict__ ws) {
    if (blockIdx.x == 128) {             // zero s[1024]
        ((vf4*)(ws + S_OFF))[threadIdx.x] = (vf4){0.f, 0.f, 0.f, 0.f};
        return;
    }
    int idx = blockIdx.x * 256 + threadIdx.x;          // 0..32767
    int which = idx >> 14;                             // 0: col, 1: row
    int e = idx & 16383;
    int o = e & 31, k = e >> 5;
    const float* src = which ? w_row : w_col;
    float* dst = ws + (which ? WTR_OFF : WTC_OFF);
    dst[e] = src[o * Kn + k];
}

// ---------------- k1: fused col/row GEMMs + dot-reduce → s ----------------
// grid (8 t-chunks, 32 b) = 256 blocks × 1024 threads (16 waves).
// wave w: phase = w>>3 (0=col, 1=row), ke = w&7 (k-eighth, 64 k); lane = t.
// vs previous 512-thread version: per-wave serial work halves (2048 FMAs,
// 64 load steps) and waves/SIMD doubles 2→4 — the kernel was latency-bound
// at 2 waves/SIMD (strided row-phase loads, 1 load per 32 FMA chain).
// k wave-uniform ⇒ weight reads stay SGPR s_loads. 16 wave-accs → LDS,
// block forms colPlus·rowPlus, atomicAdd 32 partials.
__global__ __launch_bounds__(1024) void k_fused(
    const float* __restrict__ x,      // [B][K][K]
    const float* __restrict__ bcol,
    const float* __restrict__ brow,
    float* __restrict__ ws) {
    const int chunk = blockIdx.x;     // 0..7
    const int b     = blockIdx.y;     // 0..31
    const int t0  = chunk * 64;
    const int tid = threadIdx.x;
    const int t   = tid & 63;                                   // lane
    const int wv  = __builtin_amdgcn_readfirstlane(tid >> 6);   // 0..15
    const int phase = wv >> 3;
    const int ke    = wv & 7;

    __shared__ float buf[16][64 * 33]; // 135.2 KB
    __shared__ float red2[32 * 33];    // 4.2 KB

    const float* __restrict__ xb = x + b * (Kn * Kn);

    float acc[32];
#pragma unroll
    for (int o = 0; o < 32; ++o) acc[o] = 0.f;

    if (phase == 0) {
        // col[t,o] = sum_k x[t0+t][k] * wTc[k][o] — per-thread contiguous rows
        const float4* __restrict__ xr = (const float4*)(xb + (t0 + t) * Kn) + ke * 16;
        const float* __restrict__ wk = ws + WTC_OFF + ke * 64 * 32;
#pragma unroll 2
        for (int j = 0; j < 16; ++j) {                 // 16 float4 = 64 k
            float4 v = xr[j];
            const float* __restrict__ w0 = wk + j * 128;   // uniform → s_load
#pragma unroll
            for (int o = 0; o < 32; ++o) acc[o] = fmaf(v.x, w0[o],      acc[o]);
#pragma unroll
            for (int o = 0; o < 32; ++o) acc[o] = fmaf(v.y, w0[32 + o], acc[o]);
#pragma unroll
            for (int o = 0; o < 32; ++o) acc[o] = fmaf(v.z, w0[64 + o], acc[o]);
#pragma unroll
            for (int o = 0; o < 32; ++o) acc[o] = fmaf(v.w, w0[96 + o], acc[o]);
        }
    } else {
        // row[t,o] = sum_k x[k][t0+t] * wTr[k][o] — lane-contiguous column reads
        const float* __restrict__ wr = ws + WTR_OFF;
        const int kb = ke * 64;
#pragma unroll 8
        for (int k = 0; k < 64; ++k) {
            float xv = xb[(kb + k) * Kn + t0 + t];
            const float* __restrict__ w = wr + (kb + k) * 32;  // uniform → s_load
#pragma unroll
            for (int o = 0; o < 32; ++o) acc[o] = fmaf(xv, w[o], acc[o]);
        }
    }

    // park all 16 wave-accumulators in LDS (banks: (33t+o)%32 = (t+o)%32, clean)
    {
        float* __restrict__ my = buf[wv] + t * 33;
#pragma unroll
        for (int o = 0; o < 32; ++o) my[o] = acc[o];
    }
    __syncthreads();

    // product-reduce: 1024 threads, o = tid&31, g = tid>>5 covers 2 t each
    const int o = tid & 31, g = tid >> 5;            // g: 0..31
    const float bc = bcol[o], br = brow[o];
    float sum = 0.f;
#pragma unroll
    for (int j = 0; j < 2; ++j) {
        const int tt = g * 2 + j;
        const int a  = tt * 33 + o;
        float c = buf[0][a] + buf[1][a] + buf[2][a] + buf[3][a]
                + buf[4][a] + buf[5][a] + buf[6][a] + buf[7][a] + bc;
        float r = buf[8][a]  + buf[9][a]  + buf[10][a] + buf[11][a]
                + buf[12][a] + buf[13][a] + buf[14][a] + buf[15][a] + br;
        sum = fmaf(c, r, sum);
    }
    red2[g * 33 + o] = sum;
    __syncthreads();
    if (tid < 32) {
        float s = 0.f;
#pragma unroll
        for (int j = 0; j < 32; ++j) s += red2[j * 33 + tid];
        atomicAdd(ws + S_OFF + b * 32 + tid, s);
    }
}

// ---------------- k2: broadcast s to (B,C,512,512) ----------------
// Fill-shaped streaming store kernel: 4096 blocks × 256 threads.
// Each block owns a contiguous 256 KB quarter of one (b,o) plane; each wave
// streams a contiguous 64 KB ascending region with plain (cached) float4
// stores — 1 KB per store instruction, back-to-back. Runs within ~10% of the
// harness fill's own 6.27 TB/s.
__global__ __launch_bounds__(256) void k_broadcast(const float* __restrict__ ws,
                                                   float* __restrict__ out) {
    const int bo   = blockIdx.x >> 2;            // 0..1023 (wave-uniform s)
    const int part = blockIdx.x & 3;             // quarter of the 512x512 plane
    const int lane = threadIdx.x & 63;
    const int wv   = threadIdx.x >> 6;
    const float sval = ws[S_OFF + bo];           // uniform → s_load
    vf4 v = (vf4){sval, sval, sval, sval};
    vf4* __restrict__ out4 =
        (vf4*)out + (size_t)bo * 65536 + (size_t)part * 16384
                  + (size_t)wv * 4096 + lane;
#pragma unroll
    for (int j = 0; j < 64; ++j)
        out4[j * 64] = v;                        // contiguous 1 KB/wave/store
}

extern "C" void kernel_launch(void* const* d_in, const int* in_sizes, int n_in,
                              void* d_out, int out_size, void* d_ws, size_t ws_size,
                              hipStream_t stream) {
    const float* x     = (const float*)d_in[0];
    const float* w_col = (const float*)d_in[1];
    const float* b_col = (const float*)d_in[2];
    const float* w_row = (const float*)d_in[3];
    const float* b_row = (const float*)d_in[4];
    float* out = (float*)d_out;
    float* ws  = (float*)d_ws;

    hipLaunchKernelGGL(k_prep, dim3(129), dim3(256), 0, stream, w_col, w_row, ws);
    hipLaunchKernelGGL(k_fused, dim3(8, 32), dim3(1024), 0, stream, x, b_col, b_row, ws);
    hipLaunchKernelGGL(k_broadcast, dim3(4096), dim3(256), 0, stream, ws, out);
}